// Round 1
// baseline (1433.386 us; speedup 1.0000x reference)
//
#include <hip/hip_runtime.h>
#include <math.h>

// Problem constants (from reference)
#define H 1024
#define V 10000
#define L 256
#define B 512

// ---------------------------------------------------------------------------
// Block-wide reductions (blockDim.x == 256)
// ---------------------------------------------------------------------------
__device__ __forceinline__ float bred_max(float v, float* red, int tid) {
    red[tid] = v;
    __syncthreads();
    #pragma unroll
    for (int s = 128; s > 0; s >>= 1) {
        if (tid < s) red[tid] = fmaxf(red[tid], red[tid + s]);
        __syncthreads();
    }
    float r = red[0];
    __syncthreads();
    return r;
}

__device__ __forceinline__ float bred_sum(float v, float* red, int tid) {
    red[tid] = v;
    __syncthreads();
    #pragma unroll
    for (int s = 128; s > 0; s >>= 1) {
        if (tid < s) red[tid] = red[tid] + red[tid + s];
        __syncthreads();
    }
    float r = red[0];
    __syncthreads();
    return r;
}

// ---------------------------------------------------------------------------
// K1: embedding gather + attention logits + softmax.
// 2 batch rows per block (256 blocks, 256 threads). Each thread owns one l.
// Side effect: writes embedded row into xcat[:, 0:H] (input to comb GEMM).
// ---------------------------------------------------------------------------
__global__ __launch_bounds__(256) void attn_kernel(
    const int* __restrict__ ids, const float* __restrict__ emb,
    const float* __restrict__ hidden, const float* __restrict__ attn_w,
    const float* __restrict__ attn_b, float* __restrict__ aw_out,
    float* __restrict__ xcat) {
    __shared__ float sm[2][2 * H];   // [embedded | hidden] for 2 rows (16 KB)
    __shared__ float red[256];
    const int tid = threadIdx.x;
    const int b0 = blockIdx.x * 2;

    #pragma unroll
    for (int bi = 0; bi < 2; bi++) {
        const int b = b0 + bi;
        const int row = ids[b];
        for (int k = tid; k < H; k += 256) {
            float e = emb[(size_t)row * H + k];
            sm[bi][k] = e;
            xcat[(size_t)b * (2 * H) + k] = e;          // embedded half of comb input
            sm[bi][H + k] = hidden[(size_t)b * H + k];
        }
    }
    __syncthreads();

    const int l = tid;
    float acc0 = attn_b[l];
    float acc1 = acc0;
    #pragma unroll 4
    for (int k = 0; k < 2 * H; k++) {
        float w = attn_w[k * L + l];   // coalesced across lanes
        acc0 = fmaf(sm[0][k], w, acc0);
        acc1 = fmaf(sm[1][k], w, acc1);
    }

    // softmax over l for each of the 2 rows
    float m0 = bred_max(acc0, red, tid);
    float e0 = expf(acc0 - m0);
    float s0 = bred_sum(e0, red, tid);
    aw_out[(size_t)b0 * L + l] = e0 / s0;

    float m1 = bred_max(acc1, red, tid);
    float e1 = expf(acc1 - m1);
    float s1 = bred_sum(e1, red, tid);
    aw_out[(size_t)(b0 + 1) * L + l] = e1 / s1;
}

// ---------------------------------------------------------------------------
// K2: attn_applied[b,h] = sum_l aw[b,l] * enc[b,l,h].  One block per b,
// 256 threads x float4 covers H=1024. This is the HBM-dominant kernel
// (512 MB streamed). Writes into xcat[:, H:2H].
// ---------------------------------------------------------------------------
__global__ __launch_bounds__(256) void apply_kernel(
    const float* __restrict__ aw, const float* __restrict__ enc,
    float* __restrict__ xcat) {
    __shared__ float w[L];
    const int tid = threadIdx.x;
    const int b = blockIdx.x;
    w[tid] = aw[(size_t)b * L + tid];
    __syncthreads();

    const float4* e4 = (const float4*)(enc + (size_t)b * L * H);
    float4 acc = make_float4(0.f, 0.f, 0.f, 0.f);
    #pragma unroll 8
    for (int l = 0; l < L; l++) {
        float4 v = e4[l * (H / 4) + tid];
        float wl = w[l];
        acc.x = fmaf(wl, v.x, acc.x);
        acc.y = fmaf(wl, v.y, acc.y);
        acc.z = fmaf(wl, v.z, acc.z);
        acc.w = fmaf(wl, v.w, acc.w);
    }
    *(float4*)(xcat + (size_t)b * (2 * H) + H + tid * 4) = acc;
}

// ---------------------------------------------------------------------------
// K3: generic fp32 GEMM  C = act(A(512 x K) @ W(K x N) + bias).
// 64x64 tile per 256-thread block, 4x4 per thread, K-chunk 16.
// As padded to 68 floats/row: keeps float4 LDS reads 16B-aligned and
// breaks the 4-way bank conflict on the transposed A-tile store.
// ACT: 0 = none, 1 = ReLU.
// ---------------------------------------------------------------------------
template <int ACT>
__global__ __launch_bounds__(256) void gemm_k(
    const float* __restrict__ A, int lda, const float* __restrict__ W,
    const float* __restrict__ bias, float* __restrict__ C, int N, int K) {
    __shared__ __align__(16) float As[16][68];
    __shared__ __align__(16) float Bs[16][64];
    const int tid = threadIdx.x;
    const int tx = tid & 15, ty = tid >> 4;
    const int bm = blockIdx.y * 64, bn = blockIdx.x * 64;

    float c[4][4];
    #pragma unroll
    for (int i = 0; i < 4; i++)
        #pragma unroll
        for (int j = 0; j < 4; j++) c[i][j] = 0.f;

    const int lm = tid >> 2;          // A row within tile (0..63)
    const int lk = (tid & 3) * 4;     // A k-offset (0,4,8,12)
    const int bk = tid >> 4;          // B k-row (0..15)
    const int bn4 = (tid & 15) * 4;   // B n-offset (0..60)
    const int colB = bn + bn4;

    for (int k0 = 0; k0 < K; k0 += 16) {
        float4 va = *(const float4*)(A + (size_t)(bm + lm) * lda + (k0 + lk));
        float4 vb = make_float4(0.f, 0.f, 0.f, 0.f);
        if (colB < N) vb = *(const float4*)(W + (size_t)(k0 + bk) * N + colB);
        As[lk + 0][lm] = va.x;
        As[lk + 1][lm] = va.y;
        As[lk + 2][lm] = va.z;
        As[lk + 3][lm] = va.w;
        *(float4*)(&Bs[bk][bn4]) = vb;
        __syncthreads();

        #pragma unroll
        for (int k = 0; k < 16; k++) {
            float4 a4 = *(const float4*)(&As[k][ty * 4]);
            float4 b4 = *(const float4*)(&Bs[k][tx * 4]);
            float av[4] = {a4.x, a4.y, a4.z, a4.w};
            float bv[4] = {b4.x, b4.y, b4.z, b4.w};
            #pragma unroll
            for (int i = 0; i < 4; i++)
                #pragma unroll
                for (int j = 0; j < 4; j++) c[i][j] = fmaf(av[i], bv[j], c[i][j]);
        }
        __syncthreads();
    }

    const int col = bn + tx * 4;
    if (col < N) {
        float4 bb = *(const float4*)(bias + col);
        float bvv[4] = {bb.x, bb.y, bb.z, bb.w};
        #pragma unroll
        for (int i = 0; i < 4; i++) {
            float4 o;
            float* op = &o.x;
            #pragma unroll
            for (int j = 0; j < 4; j++) {
                float v = c[i][j] + bvv[j];
                if (ACT == 1) v = fmaxf(v, 0.f);
                op[j] = v;
            }
            *(float4*)(C + (size_t)(bm + ty * 4 + i) * N + col) = o;
        }
    }
}

// ---------------------------------------------------------------------------
// K4: GRU gate elementwise.  nh = (1-z)*n + z*h
// ---------------------------------------------------------------------------
__global__ __launch_bounds__(256) void gates_kernel(
    const float* __restrict__ gi, const float* __restrict__ gh,
    const float* __restrict__ hidden, float* __restrict__ nh) {
    const int idx = blockIdx.x * 256 + threadIdx.x;   // B*H total
    const int b = idx >> 10;
    const int h = idx & (H - 1);
    const float* gib = gi + (size_t)b * 3 * H;
    const float* ghb = gh + (size_t)b * 3 * H;
    float r = 1.f / (1.f + expf(-(gib[h] + ghb[h])));
    float z = 1.f / (1.f + expf(-(gib[H + h] + ghb[H + h])));
    float n = tanhf(gib[2 * H + h] + r * ghb[2 * H + h]);
    float hp = hidden[idx];
    nh[idx] = (1.f - z) * n + z * hp;
}

// ---------------------------------------------------------------------------
// K5: in-place log_softmax over V=10000 per row; row cached in registers
// (40 per thread) so the row is read from HBM exactly once.
// ---------------------------------------------------------------------------
__global__ __launch_bounds__(256) void logsoftmax_kernel(float* __restrict__ logits) {
    __shared__ float red[256];
    const int tid = threadIdx.x;
    float* row = logits + (size_t)blockIdx.x * V;

    float vals[40];
    float m = -INFINITY;
    #pragma unroll
    for (int j = 0; j < 40; j++) {
        int i = tid + j * 256;
        vals[j] = (i < V) ? row[i] : -INFINITY;
        m = fmaxf(m, vals[j]);
    }
    float M = bred_max(m, red, tid);
    float s = 0.f;
    #pragma unroll
    for (int j = 0; j < 40; j++) s += expf(vals[j] - M);   // expf(-inf)=0 for pads
    float S = bred_sum(s, red, tid);
    float off = M + logf(S);
    #pragma unroll
    for (int j = 0; j < 40; j++) {
        int i = tid + j * 256;
        if (i < V) row[i] = vals[j] - off;
    }
}

// ---------------------------------------------------------------------------
// Launch
// ---------------------------------------------------------------------------
extern "C" void kernel_launch(void* const* d_in, const int* in_sizes, int n_in,
                              void* d_out, int out_size, void* d_ws, size_t ws_size,
                              hipStream_t stream) {
    const int* ids      = (const int*)d_in[0];
    const float* hidden = (const float*)d_in[1];
    const float* enc    = (const float*)d_in[2];
    const float* emb    = (const float*)d_in[3];
    const float* attn_w = (const float*)d_in[4];
    const float* attn_b = (const float*)d_in[5];
    const float* comb_w = (const float*)d_in[6];
    const float* comb_b = (const float*)d_in[7];
    const float* w_ih   = (const float*)d_in[8];
    const float* w_hh   = (const float*)d_in[9];
    const float* b_ih   = (const float*)d_in[10];
    const float* b_hh   = (const float*)d_in[11];
    const float* out_w  = (const float*)d_in[12];
    const float* out_b  = (const float*)d_in[13];

    float* out        = (float*)d_out;
    float* out_logits = out;                               // B*V
    float* out_nh     = out + (size_t)B * V;               // B*H
    float* out_aw     = out_nh + (size_t)B * H;            // B*L

    // Workspace layout (floats): 18.9 MB total
    float* ws   = (float*)d_ws;
    float* xcat = ws;                              // B x 2H  ([embedded | attn_applied])
    float* x    = xcat + (size_t)B * 2 * H;        // B x H   (comb output, relu'd)
    float* gi   = x + (size_t)B * H;               // B x 3H
    float* gh   = gi + (size_t)B * 3 * H;          // B x 3H

    // 1. embed gather + attn logits + softmax  -> attn_weights, xcat[:, :H]
    attn_kernel<<<B / 2, 256, 0, stream>>>(ids, emb, hidden, attn_w, attn_b,
                                           out_aw, xcat);
    // 2. context einsum (HBM-dominant)         -> xcat[:, H:]
    apply_kernel<<<B, 256, 0, stream>>>(out_aw, enc, xcat);
    // 3. comb GEMM + ReLU                      -> x
    gemm_k<1><<<dim3(H / 64, B / 64), 256, 0, stream>>>(xcat, 2 * H, comb_w,
                                                        comb_b, x, H, 2 * H);
    // 4/5. GRU input/hidden GEMMs              -> gi, gh
    gemm_k<0><<<dim3(3 * H / 64, B / 64), 256, 0, stream>>>(x, H, w_ih, b_ih,
                                                            gi, 3 * H, H);
    gemm_k<0><<<dim3(3 * H / 64, B / 64), 256, 0, stream>>>(hidden, H, w_hh, b_hh,
                                                            gh, 3 * H, H);
    // 6. GRU gates                             -> new_hidden (d_out region 2)
    gates_kernel<<<(B * H) / 256, 256, 0, stream>>>(gi, gh, hidden, out_nh);
    // 7. output projection                     -> logits (d_out region 0)
    gemm_k<0><<<dim3((V + 63) / 64, B / 64), 256, 0, stream>>>(out_nh, H, out_w,
                                                               out_b, out_logits,
                                                               V, H);
    // 8. in-place log_softmax                  -> out (d_out region 0)
    logsoftmax_kernel<<<B, 256, 0, stream>>>(out_logits);
}

// Round 2
// 1110.566 us; speedup vs baseline: 1.2907x; 1.2907x over previous
//
#include <hip/hip_runtime.h>
#include <math.h>

// Problem constants (from reference)
#define H 1024
#define V 10000
#define L 256
#define B 512
#define NP 10112   // V padded to multiple of 128 (79 * 128) for out-proj B-tiles

typedef __attribute__((ext_vector_type(8))) short bf16x8;   // 8 bf16 (4 VGPRs)
typedef __attribute__((ext_vector_type(4))) float floatx4;  // 4 fp32 acc

// fp32 -> bf16 round-to-nearest-even
__device__ __forceinline__ unsigned short f2b(float f) {
    union { float f; unsigned u; } v; v.f = f;
    unsigned r = v.u + 0x7FFF + ((v.u >> 16) & 1);
    return (unsigned short)(r >> 16);
}

// ---------------------------------------------------------------------------
// Block-wide reductions (blockDim.x == 256)
// ---------------------------------------------------------------------------
__device__ __forceinline__ float bred_max(float v, float* red, int tid) {
    red[tid] = v;
    __syncthreads();
    #pragma unroll
    for (int s = 128; s > 0; s >>= 1) {
        if (tid < s) red[tid] = fmaxf(red[tid], red[tid + s]);
        __syncthreads();
    }
    float r = red[0];
    __syncthreads();
    return r;
}

__device__ __forceinline__ float bred_sum(float v, float* red, int tid) {
    red[tid] = v;
    __syncthreads();
    #pragma unroll
    for (int s = 128; s > 0; s >>= 1) {
        if (tid < s) red[tid] = red[tid] + red[tid + s];
        __syncthreads();
    }
    float r = red[0];
    __syncthreads();
    return r;
}

// ---------------------------------------------------------------------------
// Convert fp32 -> bf16, 4 elems/thread (n must be multiple of 1024)
// ---------------------------------------------------------------------------
__global__ __launch_bounds__(256) void cvt_f2b_kernel(
    const float* __restrict__ src, unsigned short* __restrict__ dst) {
    int i = (blockIdx.x * 256 + threadIdx.x) * 4;
    float4 v = *(const float4*)(src + i);
    ushort4 o;
    o.x = f2b(v.x); o.y = f2b(v.y); o.z = f2b(v.z); o.w = f2b(v.w);
    *(ushort4*)(dst + i) = o;
}

// ---------------------------------------------------------------------------
// Transpose + convert: W (K x N fp32, row-major) -> Wt (n-major: N rows x K
// cols, bf16). K multiple of 32; N arbitrary (guarded). Padding rows of Wt
// (n >= N) are left as poison — harmless (only multiply into discarded cols).
// ---------------------------------------------------------------------------
__global__ __launch_bounds__(256) void transpose_cvt_kernel(
    const float* __restrict__ W, unsigned short* __restrict__ Wt, int K, int N) {
    __shared__ unsigned short t[32][33];
    const int n0 = blockIdx.x * 32, k0 = blockIdx.y * 32;
    const int tx = threadIdx.x & 31, ty = threadIdx.x >> 5;
    #pragma unroll
    for (int i = 0; i < 4; i++) {
        int k = k0 + ty + i * 8;
        int n = n0 + tx;
        unsigned short v = 0;
        if (n < N) v = f2b(W[(size_t)k * N + n]);
        t[ty + i * 8][tx] = v;
    }
    __syncthreads();
    #pragma unroll
    for (int i = 0; i < 4; i++) {
        int n = n0 + ty + i * 8;
        if (n < N) Wt[(size_t)n * K + k0 + tx] = t[tx][ty + i * 8];
    }
}

// ---------------------------------------------------------------------------
// K1: embedding gather + attention logits + softmax.
// 2 batch rows per block. Also writes embedded row (bf16) into xcat_b[:, :H].
// ---------------------------------------------------------------------------
__global__ __launch_bounds__(256) void attn_kernel(
    const int* __restrict__ ids, const float* __restrict__ emb,
    const float* __restrict__ hidden, const float* __restrict__ attn_w,
    const float* __restrict__ attn_b, float* __restrict__ aw_out,
    unsigned short* __restrict__ xcat_b) {
    __shared__ float sm[2][2 * H];
    __shared__ float red[256];
    const int tid = threadIdx.x;
    const int b0 = blockIdx.x * 2;

    #pragma unroll
    for (int bi = 0; bi < 2; bi++) {
        const int b = b0 + bi;
        const int row = ids[b];
        for (int k = tid; k < H; k += 256) {
            float e = emb[(size_t)row * H + k];
            sm[bi][k] = e;
            xcat_b[(size_t)b * (2 * H) + k] = f2b(e);
            sm[bi][H + k] = hidden[(size_t)b * H + k];
        }
    }
    __syncthreads();

    const int l = tid;
    float acc0 = attn_b[l];
    float acc1 = acc0;
    #pragma unroll 4
    for (int k = 0; k < 2 * H; k++) {
        float w = attn_w[k * L + l];
        acc0 = fmaf(sm[0][k], w, acc0);
        acc1 = fmaf(sm[1][k], w, acc1);
    }

    float m0 = bred_max(acc0, red, tid);
    float e0 = expf(acc0 - m0);
    float s0 = bred_sum(e0, red, tid);
    aw_out[(size_t)b0 * L + l] = e0 / s0;

    float m1 = bred_max(acc1, red, tid);
    float e1 = expf(acc1 - m1);
    float s1 = bred_sum(e1, red, tid);
    aw_out[(size_t)(b0 + 1) * L + l] = e1 / s1;
}

// ---------------------------------------------------------------------------
// K2: context einsum (HBM-dominant, 512 MB stream). Writes bf16 into
// xcat_b[:, H:2H].
// ---------------------------------------------------------------------------
__global__ __launch_bounds__(256) void apply_kernel(
    const float* __restrict__ aw, const float* __restrict__ enc,
    unsigned short* __restrict__ xcat_b) {
    __shared__ float w[L];
    const int tid = threadIdx.x;
    const int b = blockIdx.x;
    w[tid] = aw[(size_t)b * L + tid];
    __syncthreads();

    const float4* e4 = (const float4*)(enc + (size_t)b * L * H);
    float4 acc = make_float4(0.f, 0.f, 0.f, 0.f);
    #pragma unroll 8
    for (int l = 0; l < L; l++) {
        float4 v = e4[l * (H / 4) + tid];
        float wl = w[l];
        acc.x = fmaf(wl, v.x, acc.x);
        acc.y = fmaf(wl, v.y, acc.y);
        acc.z = fmaf(wl, v.z, acc.z);
        acc.w = fmaf(wl, v.w, acc.w);
    }
    ushort4 o;
    o.x = f2b(acc.x); o.y = f2b(acc.y); o.z = f2b(acc.z); o.w = f2b(acc.w);
    *(ushort4*)(xcat_b + (size_t)b * (2 * H) + H + tid * 4) = o;
}

// ---------------------------------------------------------------------------
// K3: bf16 MFMA GEMM.  C = act(A(M x K) @ Wt^T + bias)
//   A:  bf16, row-major (M x K), lda = row pitch (ushorts)
//   Wt: bf16, n-major (N x K)   -- pre-transposed weights, ldw = K
// Tile: 128x128 per 256-thread block, BK=32, 4 waves in 2x2, each wave
// 4x4 grid of 16x16x32 MFMAs. LDS tiles stored [dim][k] (k contiguous,
// 64 B rows): both staging writes and fragment reads are contiguous-1KB
// per wave => conflict-free.
// blockIdx.z selects between two independent GEMMs (for the fused GRU pair).
// ACT: 1 = ReLU. OUT_BF16: 1 = write bf16 to Cb, else fp32 to Cf.
// ---------------------------------------------------------------------------
#define BMT 128
#define BNT 128
#define BKT 32

template <int ACT, int OUT_BF16>
__global__ __launch_bounds__(256) void gemm_mfma(
    const unsigned short* __restrict__ A0, const unsigned short* __restrict__ A1,
    int lda,
    const unsigned short* __restrict__ W0, const unsigned short* __restrict__ W1,
    const float* __restrict__ bias0, const float* __restrict__ bias1,
    float* __restrict__ C0f, float* __restrict__ C1f,
    unsigned short* __restrict__ C0b, unsigned short* __restrict__ C1b,
    int ldc, int K, int nreal) {
    __shared__ __align__(16) unsigned short As[BMT * BKT];  // [m][k]
    __shared__ __align__(16) unsigned short Bs[BNT * BKT];  // [n][k]

    const unsigned short* A  = blockIdx.z ? A1 : A0;
    const unsigned short* Wt = blockIdx.z ? W1 : W0;
    const float* bias        = blockIdx.z ? bias1 : bias0;
    float* Cf                = blockIdx.z ? C1f : C0f;
    unsigned short* Cb       = blockIdx.z ? C1b : C0b;

    const int tid = threadIdx.x;
    const int lane = tid & 63;
    const int wave = tid >> 6;          // 0..3
    const int wm = wave & 1, wn = wave >> 1;
    const int ln = lane & 15, quad = lane >> 4;
    const int bm = blockIdx.y * BMT, bn = blockIdx.x * BNT;

    // staging map: thread t covers tile elements t and t+256 of 512 16B-chunks
    const int r0 = tid >> 2;            // row 0..63
    const int c0 = (tid & 3) * 8;       // k-offset in ushorts (0,8,16,24)
    const unsigned short* Ap0 = A + (size_t)(bm + r0) * lda + c0;
    const unsigned short* Ap1 = Ap0 + (size_t)64 * lda;
    const unsigned short* Bp0 = Wt + (size_t)(bn + r0) * K + c0;
    const unsigned short* Bp1 = Bp0 + (size_t)64 * K;

    floatx4 acc[4][4];
    #pragma unroll
    for (int i = 0; i < 4; i++)
        #pragma unroll
        for (int j = 0; j < 4; j++) acc[i][j] = (floatx4)0.0f;

    uint4 pa0 = *(const uint4*)(Ap0);
    uint4 pa1 = *(const uint4*)(Ap1);
    uint4 pb0 = *(const uint4*)(Bp0);
    uint4 pb1 = *(const uint4*)(Bp1);

    for (int k0 = 0; k0 < K; k0 += BKT) {
        *(uint4*)(&As[r0 * BKT + c0])        = pa0;
        *(uint4*)(&As[(r0 + 64) * BKT + c0]) = pa1;
        *(uint4*)(&Bs[r0 * BKT + c0])        = pb0;
        *(uint4*)(&Bs[(r0 + 64) * BKT + c0]) = pb1;
        __syncthreads();

        const int kn = k0 + BKT;
        if (kn < K) {   // prefetch next chunk; overlaps the MFMAs below
            pa0 = *(const uint4*)(Ap0 + kn);
            pa1 = *(const uint4*)(Ap1 + kn);
            pb0 = *(const uint4*)(Bp0 + kn);
            pb1 = *(const uint4*)(Bp1 + kn);
        }

        bf16x8 af[4], bfr[4];
        #pragma unroll
        for (int i = 0; i < 4; i++) {
            af[i]  = *(const bf16x8*)(&As[(wm * 64 + i * 16 + ln) * BKT + quad * 8]);
            bfr[i] = *(const bf16x8*)(&Bs[(wn * 64 + i * 16 + ln) * BKT + quad * 8]);
        }
        #pragma unroll
        for (int mi = 0; mi < 4; mi++)
            #pragma unroll
            for (int ni = 0; ni < 4; ni++)
                acc[mi][ni] = __builtin_amdgcn_mfma_f32_16x16x32_bf16(
                    af[mi], bfr[ni], acc[mi][ni], 0, 0, 0);
        __syncthreads();
    }

    // Epilogue. C/D layout: col = ln, row = quad*4 + reg.
    #pragma unroll
    for (int ni = 0; ni < 4; ni++) {
        const int col = bn + wn * 64 + ni * 16 + ln;
        const bool ok = col < nreal;
        float bv = ok ? bias[col] : 0.f;
        #pragma unroll
        for (int mi = 0; mi < 4; mi++) {
            const int rowb = bm + wm * 64 + mi * 16 + quad * 4;
            #pragma unroll
            for (int r = 0; r < 4; r++) {
                float v = acc[mi][ni][r] + bv;
                if (ACT == 1) v = fmaxf(v, 0.f);
                if (ok) {
                    if (OUT_BF16)
                        Cb[(size_t)(rowb + r) * ldc + col] = f2b(v);
                    else
                        Cf[(size_t)(rowb + r) * ldc + col] = v;
                }
            }
        }
    }
}

// ---------------------------------------------------------------------------
// K4: GRU gates. nh = (1-z)*n + z*h. Writes fp32 (d_out) + bf16 (out-proj A).
// ---------------------------------------------------------------------------
__global__ __launch_bounds__(256) void gates_kernel(
    const float* __restrict__ gi, const float* __restrict__ gh,
    const float* __restrict__ hidden, float* __restrict__ nh,
    unsigned short* __restrict__ nh_b) {
    const int idx = blockIdx.x * 256 + threadIdx.x;   // B*H total
    const int b = idx >> 10;
    const int h = idx & (H - 1);
    const float* gib = gi + (size_t)b * 3 * H;
    const float* ghb = gh + (size_t)b * 3 * H;
    float r = 1.f / (1.f + expf(-(gib[h] + ghb[h])));
    float z = 1.f / (1.f + expf(-(gib[H + h] + ghb[H + h])));
    float n = tanhf(gib[2 * H + h] + r * ghb[2 * H + h]);
    float hp = hidden[idx];
    float v = (1.f - z) * n + z * hp;
    nh[idx] = v;
    nh_b[idx] = f2b(v);
}

// ---------------------------------------------------------------------------
// K5: in-place log_softmax over V per row (row pitch V, in d_out).
// ---------------------------------------------------------------------------
__global__ __launch_bounds__(256) void logsoftmax_kernel(float* __restrict__ logits) {
    __shared__ float red[256];
    const int tid = threadIdx.x;
    float* row = logits + (size_t)blockIdx.x * V;

    float vals[40];
    float m = -INFINITY;
    #pragma unroll
    for (int j = 0; j < 40; j++) {
        int i = tid + j * 256;
        vals[j] = (i < V) ? row[i] : -INFINITY;
        m = fmaxf(m, vals[j]);
    }
    float M = bred_max(m, red, tid);
    float s = 0.f;
    #pragma unroll
    for (int j = 0; j < 40; j++) s += expf(vals[j] - M);
    float S = bred_sum(s, red, tid);
    float off = M + logf(S);
    #pragma unroll
    for (int j = 0; j < 40; j++) {
        int i = tid + j * 256;
        if (i < V) row[i] = vals[j] - off;
    }
}

// ---------------------------------------------------------------------------
// Launch
// ---------------------------------------------------------------------------
extern "C" void kernel_launch(void* const* d_in, const int* in_sizes, int n_in,
                              void* d_out, int out_size, void* d_ws, size_t ws_size,
                              hipStream_t stream) {
    const int* ids      = (const int*)d_in[0];
    const float* hidden = (const float*)d_in[1];
    const float* enc    = (const float*)d_in[2];
    const float* emb    = (const float*)d_in[3];
    const float* attn_w = (const float*)d_in[4];
    const float* attn_b = (const float*)d_in[5];
    const float* comb_w = (const float*)d_in[6];
    const float* comb_b = (const float*)d_in[7];
    const float* w_ih   = (const float*)d_in[8];
    const float* w_hh   = (const float*)d_in[9];
    const float* b_ih   = (const float*)d_in[10];
    const float* b_hh   = (const float*)d_in[11];
    const float* out_w  = (const float*)d_in[12];
    const float* out_b  = (const float*)d_in[13];

    float* out        = (float*)d_out;
    float* out_logits = out;                               // B*V fp32
    float* out_nh     = out + (size_t)B * V;               // B*H
    float* out_aw     = out_nh + (size_t)B * H;            // B*L

    // Workspace layout (~55 MB)
    char* ws = (char*)d_ws;
    unsigned short* h_b    = (unsigned short*)ws;                 ws += (size_t)B * H * 2;
    unsigned short* x_b    = (unsigned short*)ws;                 ws += (size_t)B * H * 2;
    unsigned short* h2_b   = (unsigned short*)ws;                 ws += (size_t)B * H * 2;
    unsigned short* xcat_b = (unsigned short*)ws;                 ws += (size_t)B * 2 * H * 2;
    float* gi              = (float*)ws;                          ws += (size_t)B * 3 * H * 4;
    float* gh              = (float*)ws;                          ws += (size_t)B * 3 * H * 4;
    unsigned short* combwt = (unsigned short*)ws;                 ws += (size_t)H * 2 * H * 2;
    unsigned short* wiht   = (unsigned short*)ws;                 ws += (size_t)3 * H * H * 2;
    unsigned short* whht   = (unsigned short*)ws;                 ws += (size_t)3 * H * H * 2;
    unsigned short* outwt  = (unsigned short*)ws;                 ws += (size_t)NP * H * 2;

    // Weight conversion + transpose (every call; inputs restored per call)
    cvt_f2b_kernel<<<(B * H) / 1024, 256, 0, stream>>>(hidden, h_b);
    transpose_cvt_kernel<<<dim3(1024 / 32, 2048 / 32), 256, 0, stream>>>(comb_w, combwt, 2 * H, H);
    transpose_cvt_kernel<<<dim3(3072 / 32, 1024 / 32), 256, 0, stream>>>(w_ih, wiht, H, 3 * H);
    transpose_cvt_kernel<<<dim3(3072 / 32, 1024 / 32), 256, 0, stream>>>(w_hh, whht, H, 3 * H);
    transpose_cvt_kernel<<<dim3((V + 31) / 32, 1024 / 32), 256, 0, stream>>>(out_w, outwt, H, V);

    // 1. embed gather + attn softmax -> out_aw, xcat_b[:, :H]
    attn_kernel<<<B / 2, 256, 0, stream>>>(ids, emb, hidden, attn_w, attn_b,
                                           out_aw, xcat_b);
    // 2. context einsum -> xcat_b[:, H:]
    apply_kernel<<<B, 256, 0, stream>>>(out_aw, enc, xcat_b);
    // 3. comb GEMM + ReLU -> x_b (bf16)
    gemm_mfma<1, 1><<<dim3(H / BNT, B / BMT, 1), 256, 0, stream>>>(
        xcat_b, xcat_b, 2 * H, combwt, combwt, comb_b, comb_b,
        nullptr, nullptr, x_b, x_b, H, 2 * H, H);
    // 4. GRU input+hidden GEMMs (fused via grid.z) -> gi, gh (fp32)
    gemm_mfma<0, 0><<<dim3(3 * H / BNT, B / BMT, 2), 256, 0, stream>>>(
        x_b, h_b, H, wiht, whht, b_ih, b_hh,
        gi, gh, nullptr, nullptr, 3 * H, H, 3 * H);
    // 5. GRU gates -> out_nh (fp32) + h2_b (bf16)
    gates_kernel<<<(B * H) / 256, 256, 0, stream>>>(gi, gh, hidden, out_nh, h2_b);
    // 6. output projection -> logits (fp32, pitch V, in d_out)
    gemm_mfma<0, 0><<<dim3(NP / BNT, B / BMT, 1), 256, 0, stream>>>(
        h2_b, h2_b, H, outwt, outwt, out_b, out_b,
        out_logits, out_logits, nullptr, nullptr, V, H, V);
    // 7. in-place log_softmax
    logsoftmax_kernel<<<B, 256, 0, stream>>>(out_logits);
}